// Round 11
// baseline (291.586 us; speedup 1.0000x reference)
//
#include <hip/hip_runtime.h>
#include <hip/hip_bf16.h>

#define BB 4
#define TT 4096
#define CC 1024
#define HH 64

// q is pre-scaled by 0.125*log2(e) at projection time; attn works in exp2 domain.
#define QSCALE 0.18033688011112042f
#define FIXMAX2 23.083120654223414f    // 16 * log2(e)

typedef __attribute__((ext_vector_type(8))) short short8;   // 8 x bf16 (4 VGPRs)
typedef __attribute__((ext_vector_type(4))) float floatx4;  // MFMA C/D

__device__ __forceinline__ ushort f2bf(float f) {
    union { float f; unsigned u; } a; a.f = f;
    const unsigned u = a.u;
    return (ushort)((u + 0x7fffu + ((u >> 16) & 1u)) >> 16);   // RNE
}
__device__ __forceinline__ float bf2f(ushort h) {
    union { unsigned u; float f; } a; a.u = ((unsigned)h) << 16; return a.f;
}

// ---------------------------------------------------------------------------
// Kernel A: W [1024 x 64] f32 -> wT [3*64][1024] bf16 (transposed, unified).
// grid = 3 mats x 16 k-tiles = 48 blocks.  (measured cheap)
// ---------------------------------------------------------------------------
__global__ __launch_bounds__(256)
void wtrans_kernel(const float* __restrict__ Wq, const float* __restrict__ Wk,
                   const float* __restrict__ Wv, ushort* __restrict__ wT)
{
    __shared__ ushort tile[64 * 72];
    const int tid = threadIdx.x;
    const int mat = blockIdx.x >> 4, kt = blockIdx.x & 15;
    const float* W = (mat == 0) ? Wq : (mat == 1) ? Wk : Wv;
    #pragma unroll
    for (int it = 0; it < 16; ++it) {
        const int idx = it * 256 + tid;
        const int r = idx >> 6, c = idx & 63;
        tile[c * 72 + r] = f2bf(W[(size_t)(kt * 64 + r) * 64 + c]);
    }
    __syncthreads();
    #pragma unroll
    for (int it = 0; it < 16; ++it) {
        const int idx = it * 256 + tid;
        const int n = idx >> 6, kk = idx & 63;
        wT[((size_t)mat * 64 + n) * 1024 + kt * 64 + kk] = tile[n * 72 + kk];
    }
}

// ---------------------------------------------------------------------------
// Kernel B (v7): R9's measured-good geometry (1024 blocks x 256 thr, M=16,
// BK=64, padded-72 LDS) + register prefetch of chunk kc+1, with
// __launch_bounds__(256,4) -> 128-VGPR cap so the prefetch regs (28) fit
// without the scratch spill that killed R10 (VGPR=28, WRITE_SIZE=90MB).
// ---------------------------------------------------------------------------
__global__ __launch_bounds__(256, 4)
void qkv_mfma_kernel(const float* __restrict__ x, const ushort* __restrict__ wT,
                     const float* __restrict__ bq, const float* __restrict__ bk,
                     const float* __restrict__ bv,
                     ushort* __restrict__ q, ushort* __restrict__ k,
                     ushort* __restrict__ vT)
{
    __shared__ ushort xs [16 * 72];    // 2.3 KB
    __shared__ ushort ws_[192 * 72];   // 27.6 KB

    const int tid = threadIdx.x, w = tid >> 6, lane = tid & 63;
    const int m = lane & 15, quad = lane >> 4;
    const int row0 = blockIdx.x * 16;

    floatx4 acc[3];
    #pragma unroll
    for (int i = 0; i < 3; ++i) acc[i] = (floatx4){0.f, 0.f, 0.f, 0.f};

    // staging coords: x = 1 float4/thread, W = 6 uint4/thread
    const int xr = tid >> 4, xseg = tid & 15;

    float4 pfx;
    uint4  pfw[6];
    {   // prologue: load chunk 0 into regs
        pfx = *(const float4*)(x + (size_t)(row0 + xr) * CC + xseg * 4);
        #pragma unroll
        for (int it = 0; it < 6; ++it) {
            const int idx = it * 256 + tid;
            const int r = idx >> 3, g = idx & 7;
            pfw[it] = *(const uint4*)(wT + (size_t)r * 1024 + g * 8);
        }
    }

    for (int kc = 0; kc < 16; ++kc) {
        __syncthreads();        // protect prior chunk's LDS reads
        {   // write prefetched chunk to LDS (f32 -> bf16 for x)
            ushort4 p;
            p.x = f2bf(pfx.x); p.y = f2bf(pfx.y); p.z = f2bf(pfx.z); p.w = f2bf(pfx.w);
            *(ushort4*)(xs + xr * 72 + xseg * 4) = p;
            #pragma unroll
            for (int it = 0; it < 6; ++it) {
                const int idx = it * 256 + tid;
                const int r = idx >> 3, g = idx & 7;
                *(uint4*)(ws_ + r * 72 + g * 8) = pfw[it];
            }
        }
        __syncthreads();
        if (kc + 1 < 16) {      // prefetch next chunk; overlaps MFMA below
            const int k0 = (kc + 1) * 64;
            pfx = *(const float4*)(x + (size_t)(row0 + xr) * CC + k0 + xseg * 4);
            #pragma unroll
            for (int it = 0; it < 6; ++it) {
                const int idx = it * 256 + tid;
                const int r = idx >> 3, g = idx & 7;
                pfw[it] = *(const uint4*)(wT + (size_t)r * 1024 + k0 + g * 8);
            }
        }

        #pragma unroll
        for (int ks_ = 0; ks_ < 2; ++ks_) {
            const short8 a = *(const short8*)(xs + m * 72 + ks_ * 32 + quad * 8);
            #pragma unroll
            for (int j = 0; j < 3; ++j) {
                const short8 b_ = *(const short8*)(ws_ + (w * 48 + j * 16 + m) * 72 + ks_ * 32 + quad * 8);
                acc[j] = __builtin_amdgcn_mfma_f32_16x16x32_bf16(a, b_, acc[j], 0, 0, 0);
            }
        }
    }

    // epilogue.  C-layout: row = quad*4 + r, col = nt*16 + m (nt = 3w + j).
    const int gr0 = row0 + quad * 4;
    const int b_ = gr0 >> 12, t0 = gr0 & (TT - 1);
    #pragma unroll
    for (int j = 0; j < 3; ++j) {
        const int nt = w * 3 + j;
        const int mat = nt >> 2;
        const int c = (nt & 3) * 16 + m;
        const float bias = (mat == 0) ? bq[c] : (mat == 1) ? bk[c] : bv[c];
        if (mat == 0) {
            #pragma unroll
            for (int r = 0; r < 4; ++r)
                q[(size_t)(gr0 + r) * HH + c] = f2bf((acc[j][r] + bias) * QSCALE);
        } else if (mat == 1) {
            #pragma unroll
            for (int r = 0; r < 4; ++r)
                k[(size_t)(gr0 + r) * HH + c] = f2bf(acc[j][r] + bias);
        } else {
            ushort4 pv;
            pv.x = f2bf(acc[j][0] + bias); pv.y = f2bf(acc[j][1] + bias);
            pv.z = f2bf(acc[j][2] + bias); pv.w = f2bf(acc[j][3] + bias);
            *(ushort4*)(vT + ((size_t)b_ * HH + c) * TT + t0) = pv;
        }
    }
}

// ---------------------------------------------------------------------------
// Kernel C (v7, unchanged from R9): causal flash attention, 8-way split-s,
// fixed-max exp2-domain softmax.  grid = 4*64*8 = 2048 blocks x 256 thr.
// ---------------------------------------------------------------------------
__global__ __launch_bounds__(256)
void attn_mfma_kernel(const ushort* __restrict__ q, const ushort* __restrict__ k,
                      const ushort* __restrict__ vT,
                      float* __restrict__ partL, ushort* __restrict__ partO)
{
    __shared__ ushort ks[64 * 72];
    __shared__ ushort vs[64 * 72];        // [d][s] (from vT)
    __shared__ ushort ps[4][16 * 72];     // wave-private P

    const int tid = threadIdx.x, w = tid >> 6, lane = tid & 63;
    const int m = lane & 15, quad = lane >> 4;
    const int pid = blockIdx.x;
    const int job = pid >> 3, split = pid & 7;
    const int b = job >> 6, tile = job & 63;
    const int i0 = tile * 64;
    const int nch = tile + 1;
    const int lo = (nch * split) >> 3, hi = (nch * (split + 1)) >> 3;

    const size_t qrow = ((size_t)b * TT + i0 + w * 16 + m) * HH;
    const uint4 aq0u = *(const uint4*)(q + qrow + quad * 8);
    const uint4 aq1u = *(const uint4*)(q + qrow + 32 + quad * 8);
    const short8 aq0 = *(const short8*)&aq0u;
    const short8 aq1 = *(const short8*)&aq1u;

    float lrow[4] = {0.f, 0.f, 0.f, 0.f};
    floatx4 oacc[4];
    #pragma unroll
    for (int nt = 0; nt < 4; ++nt) oacc[nt] = (floatx4){0.f, 0.f, 0.f, 0.f};

    const int iq0 = i0 + w * 16;
    for (int ch = lo; ch < hi; ++ch) {
        const int s0 = ch * 64;
        __syncthreads();
        const size_t kb = ((size_t)b * TT + s0) * HH;
        #pragma unroll
        for (int it = 0; it < 2; ++it) {
            const int t2 = it * 256 + tid;
            const int r = t2 >> 3, seg = t2 & 7;
            *(uint4*)(ks + r * 72 + seg * 8) = *(const uint4*)(k + kb + (size_t)r * HH + seg * 8);
            *(uint4*)(vs + r * 72 + seg * 8) = *(const uint4*)(vT + ((size_t)b * HH + r) * TT + s0 + seg * 8);
        }
        __syncthreads();

        floatx4 sc[4];
        #pragma unroll
        for (int nt = 0; nt < 4; ++nt) {
            const short8 b0 = *(const short8*)(ks + (nt * 16 + m) * 72 + quad * 8);
            const short8 b1 = *(const short8*)(ks + (nt * 16 + m) * 72 + 32 + quad * 8);
            floatx4 s_ = (floatx4){0.f, 0.f, 0.f, 0.f};
            s_ = __builtin_amdgcn_mfma_f32_16x16x32_bf16(aq0, b0, s_, 0, 0, 0);
            s_ = __builtin_amdgcn_mfma_f32_16x16x32_bf16(aq1, b1, s_, 0, 0, 0);
            sc[nt] = s_;
        }

        // fixed-max exp2-domain softmax.  p = 2^(s' - FIXMAX2); masked -> 0.
        const bool need_mask = (s0 + 63 > iq0);     // wave-uniform: diagonal chunk only
        #pragma unroll
        for (int r = 0; r < 4; ++r) {
            float t0 = sc[0][r] - FIXMAX2;
            float t1 = sc[1][r] - FIXMAX2;
            float t2 = sc[2][r] - FIXMAX2;
            float t3 = sc[3][r] - FIXMAX2;
            if (need_mask) {
                const int dlim = iq0 + quad * 4 + r - s0 - m;   // mask iff c*16 > dlim
                if (0  > dlim) t0 = -1e30f;
                if (16 > dlim) t1 = -1e30f;
                if (32 > dlim) t2 = -1e30f;
                if (48 > dlim) t3 = -1e30f;
            }
            const float p0 = __builtin_amdgcn_exp2f(t0);
            const float p1 = __builtin_amdgcn_exp2f(t1);
            const float p2 = __builtin_amdgcn_exp2f(t2);
            const float p3 = __builtin_amdgcn_exp2f(t3);
            lrow[r] += (p0 + p1) + (p2 + p3);
            ushort* pr = ps[w] + (quad * 4 + r) * 72;
            pr[m]      = f2bf(p0);
            pr[16 + m] = f2bf(p1);
            pr[32 + m] = f2bf(p2);
            pr[48 + m] = f2bf(p3);
        }

        // PV: A = P (LDS round-trip), B = vT rows
        #pragma unroll
        for (int ks_ = 0; ks_ < 2; ++ks_) {
            const short8 ap = *(const short8*)(ps[w] + m * 72 + ks_ * 32 + quad * 8);
            #pragma unroll
            for (int nt = 0; nt < 4; ++nt) {
                const short8 bv_ = *(const short8*)(vs + (nt * 16 + m) * 72 + ks_ * 32 + quad * 8);
                oacc[nt] = __builtin_amdgcn_mfma_f32_16x16x32_bf16(ap, bv_, oacc[nt], 0, 0, 0);
            }
        }
    }

    // reduce lrow across the 16 m-lanes (rows live in (quad, r))
    #pragma unroll
    for (int r = 0; r < 4; ++r) {
        float s = lrow[r];
        s += __shfl_xor(s, 1); s += __shfl_xor(s, 2);
        s += __shfl_xor(s, 4); s += __shfl_xor(s, 8);
        lrow[r] = s;
    }
    if (m == 0) {
        #pragma unroll
        for (int r = 0; r < 4; ++r)
            partL[(size_t)pid * 64 + w * 16 + quad * 4 + r] = lrow[r];
    }
    ushort* po = partO + ((size_t)pid * 64 + w * 16) * 64;
    #pragma unroll
    for (int r = 0; r < 4; ++r) {
        const int row = quad * 4 + r;
        #pragma unroll
        for (int nt = 0; nt < 4; ++nt)
            po[row * 64 + nt * 16 + m] = f2bf(oacc[nt][r]);
    }
}

// ---------------------------------------------------------------------------
// Kernel D (v2, unchanged from R9): combine 8 split partials (shared fixed
// max -> plain sums).  grid = 256 (job), 256 threads.
// ---------------------------------------------------------------------------
__global__ __launch_bounds__(256)
void attn_combine_kernel(const float* __restrict__ partL,
                         const ushort* __restrict__ partO, float* __restrict__ out)
{
    const int job = blockIdx.x;
    const int tid = threadIdx.x;
    const int row = tid >> 2, dq = tid & 3;

    float L = 0.f;
    #pragma unroll
    for (int s = 0; s < 8; ++s) L += partL[(size_t)(job * 8 + s) * 64 + row];
    const float inv = 1.f / L;

    float o[16];
    #pragma unroll
    for (int i = 0; i < 16; ++i) o[i] = 0.f;
    #pragma unroll
    for (int s = 0; s < 8; ++s) {
        const ushort* po = partO + (((size_t)(job * 8 + s) * 64 + row) * 64 + dq * 16);
        #pragma unroll
        for (int i2 = 0; i2 < 2; ++i2) {
            const ushort4 pa = *(const ushort4*)(po + i2 * 8);
            const ushort4 pb = *(const ushort4*)(po + i2 * 8 + 4);
            o[i2*8+0] += bf2f(pa.x); o[i2*8+1] += bf2f(pa.y);
            o[i2*8+2] += bf2f(pa.z); o[i2*8+3] += bf2f(pa.w);
            o[i2*8+4] += bf2f(pb.x); o[i2*8+5] += bf2f(pb.y);
            o[i2*8+6] += bf2f(pb.z); o[i2*8+7] += bf2f(pb.w);
        }
    }
    float4* dst = (float4*)(out + ((size_t)job * 64 + row) * 64 + dq * 16);
    #pragma unroll
    for (int i = 0; i < 4; ++i) {
        float4 v; v.x = o[i*4]*inv; v.y = o[i*4+1]*inv; v.z = o[i*4+2]*inv; v.w = o[i*4+3]*inv;
        dst[i] = v;
    }
}

extern "C" void kernel_launch(void* const* d_in, const int* in_sizes, int n_in,
                              void* d_out, int out_size, void* d_ws, size_t ws_size,
                              hipStream_t stream) {
    (void)in_sizes; (void)n_in; (void)out_size; (void)ws_size;
    const float* x  = (const float*)d_in[0];
    // d_in[1] = causal mask, structural -> unused
    const float* Wq = (const float*)d_in[2];
    const float* bq = (const float*)d_in[3];
    const float* Wk = (const float*)d_in[4];
    const float* bk = (const float*)d_in[5];
    const float* Wv = (const float*)d_in[6];
    const float* bv = (const float*)d_in[7];
    float* out = (float*)d_out;

    char* ws = (char*)d_ws;
    ushort* wT    = (ushort*)ws;                          // 384 KB @ 0
    ushort* qb    = (ushort*)(ws + 393216);               // 2 MB
    ushort* kb    = qb + (size_t)BB * TT * HH;            // 2 MB
    ushort* vTb   = kb + (size_t)BB * TT * HH;            // 2 MB
    float*  partL = (float*) (ws + 6684672);              // 512 KB (2048*64*4)
    ushort* partO = (ushort*)(ws + 7208960);              // 16.8 MB (total ~24 MB)

    wtrans_kernel   <<<48, 256, 0, stream>>>(Wq, Wk, Wv, wT);
    qkv_mfma_kernel <<<(BB * TT) / 16, 256, 0, stream>>>(x, wT, bq, bk, bv, qb, kb, vTb);
    attn_mfma_kernel<<<BB * 64 * 8, 256, 0, stream>>>(qb, kb, vTb, partL, partO);
    attn_combine_kernel<<<BB * 64, 256, 0, stream>>>(partL, partO, out);
}

// Round 12
// 204.941 us; speedup vs baseline: 1.4228x; 1.4228x over previous
//
#include <hip/hip_runtime.h>
#include <hip/hip_bf16.h>

#define BB 4
#define TT 4096
#define CC 1024
#define HH 64

// q is pre-scaled by 0.125*log2(e) at projection time; attn works in exp2 domain.
#define QSCALE 0.18033688011112042f
#define FIXMAX2 23.083120654223414f    // 16 * log2(e)

typedef __attribute__((ext_vector_type(8))) short short8;   // 8 x bf16 (4 VGPRs)
typedef __attribute__((ext_vector_type(4))) float floatx4;  // MFMA C/D

__device__ __forceinline__ ushort f2bf(float f) {
    union { float f; unsigned u; } a; a.f = f;
    const unsigned u = a.u;
    return (ushort)((u + 0x7fffu + ((u >> 16) & 1u)) >> 16);   // RNE
}
__device__ __forceinline__ float bf2f(ushort h) {
    union { unsigned u; float f; } a; a.u = ((unsigned)h) << 16; return a.f;
}
// async global->LDS DMA, 16B per lane.  LDS dest = l (wave-uniform) + lane*16.
__device__ __forceinline__ void load_lds16(const ushort* g, ushort* l) {
    __builtin_amdgcn_global_load_lds(
        (const __attribute__((address_space(1))) unsigned int*)g,
        (__attribute__((address_space(3))) unsigned int*)l, 16, 0, 0);
}

// ---------------------------------------------------------------------------
// Kernel A: W [1024 x 64] f32 -> wT [3*64][1024] bf16 (transposed, unified).
// grid = 3 mats x 16 k-tiles = 48 blocks.  (measured cheap)
// ---------------------------------------------------------------------------
__global__ __launch_bounds__(256)
void wtrans_kernel(const float* __restrict__ Wq, const float* __restrict__ Wk,
                   const float* __restrict__ Wv, ushort* __restrict__ wT)
{
    __shared__ ushort tile[64 * 72];
    const int tid = threadIdx.x;
    const int mat = blockIdx.x >> 4, kt = blockIdx.x & 15;
    const float* W = (mat == 0) ? Wq : (mat == 1) ? Wk : Wv;
    #pragma unroll
    for (int it = 0; it < 16; ++it) {
        const int idx = it * 256 + tid;
        const int r = idx >> 6, c = idx & 63;
        tile[c * 72 + r] = f2bf(W[(size_t)(kt * 64 + r) * 64 + c]);
    }
    __syncthreads();
    #pragma unroll
    for (int it = 0; it < 16; ++it) {
        const int idx = it * 256 + tid;
        const int n = idx >> 6, kk = idx & 63;
        wT[((size_t)mat * 64 + n) * 1024 + kt * 64 + kk] = tile[n * 72 + kk];
    }
}

// ---------------------------------------------------------------------------
// Kernel B (v8): R9's measured-good geometry (1024 blocks x 256 thr, M=16,
// BK=64) with W staging via global_load_lds width=16 (async DMA, no VGPR
// round-trip -> nothing for the allocator to spill; R10/R11's register
// prefetch spilled to scratch at every occupancy target).
// W LDS is UNPADDED (DMA dest is base+lane*16) with XOR swizzle:
//   16B-group g of row r lives at group g ^ (r&7).
// Staging lane math: r = lane>>3, g = (lane&7)^(lane>>3)  (w*48, j*8 === 0 mod 8).
// Frag-read banks: (gr ^ (m&7))*4 -> all 32 banks, 2 lanes each (free).
// Frag LDS addresses are kc-invariant -> precomputed once.
// ---------------------------------------------------------------------------
__global__ __launch_bounds__(256)
void qkv_mfma_kernel(const float* __restrict__ x, const ushort* __restrict__ wT,
                     const float* __restrict__ bq, const float* __restrict__ bk,
                     const float* __restrict__ bv,
                     ushort* __restrict__ q, ushort* __restrict__ k,
                     ushort* __restrict__ vT)
{
    __shared__ ushort xs [16 * 72];     // 2.3 KB, padded (normal ds_write path)
    __shared__ ushort ws_[192 * 64];    // 24.6 KB, unpadded + XOR swizzle (DMA)

    const int tid = threadIdx.x, w = tid >> 6, lane = tid & 63;
    const int m = lane & 15, quad = lane >> 4;
    const int row0 = blockIdx.x * 16;

    floatx4 acc[3];
    #pragma unroll
    for (int i = 0; i < 3; ++i) acc[i] = (floatx4){0.f, 0.f, 0.f, 0.f};

    // per-lane W global source (element units): row = w*48 + j*8 + (lane>>3),
    // swizzled group g = (lane&7)^(lane>>3); j adds 8 rows = 8192 elements.
    const int lrow = lane >> 3;
    const int lg   = (lane & 7) ^ lrow;
    const ushort* gw = wT + (size_t)(w * 48 + lrow) * 1024 + lg * 8;
    ushort* lbase = ws_ + w * 6 * 512;          // per-issue dest: +512 ushort (1KB)

    // x staging coords (1 float4/thread)
    const int xr = tid >> 4, xseg = tid & 15;

    // precomputed kc-invariant B-frag LDS pointers:
    // slot = (w*48 + j*16 + m)*8 + ((ks*4+quad) ^ (m&7));  addr = slot*16B
    const ushort* bfp[3][2];
    #pragma unroll
    for (int j = 0; j < 3; ++j)
        #pragma unroll
        for (int ks_ = 0; ks_ < 2; ++ks_)
            bfp[j][ks_] = ws_ + ((size_t)(w * 48 + j * 16 + m) * 8 +
                                 ((ks_ * 4 + quad) ^ (m & 7))) * 8;

    for (int kc = 0; kc < 16; ++kc) {
        const int k0 = kc * 64;
        __syncthreads();        // prior chunk's LDS reads done
        // async W stage: 6 DMA issues/wave (48 rows x 128B)
        #pragma unroll
        for (int j = 0; j < 6; ++j)
            load_lds16(gw + (size_t)j * 8192 + k0, lbase + j * 512);
        // x stage: load f32, convert, ds_write
        {
            const float4 f0 = *(const float4*)(x + (size_t)(row0 + xr) * CC + k0 + xseg * 4);
            ushort4 p;
            p.x = f2bf(f0.x); p.y = f2bf(f0.y); p.z = f2bf(f0.z); p.w = f2bf(f0.w);
            *(ushort4*)(xs + xr * 72 + xseg * 4) = p;
        }
        __syncthreads();        // drains DMA (vmcnt) + ds_write (lgkmcnt)

        #pragma unroll
        for (int ks_ = 0; ks_ < 2; ++ks_) {
            const short8 a = *(const short8*)(xs + m * 72 + ks_ * 32 + quad * 8);
            #pragma unroll
            for (int j = 0; j < 3; ++j) {
                const short8 b_ = *(const short8*)bfp[j][ks_];
                acc[j] = __builtin_amdgcn_mfma_f32_16x16x32_bf16(a, b_, acc[j], 0, 0, 0);
            }
        }
    }

    // epilogue.  C-layout: row = quad*4 + r, col = nt*16 + m (nt = 3w + j).
    const int gr0 = row0 + quad * 4;
    const int b_ = gr0 >> 12, t0 = gr0 & (TT - 1);
    #pragma unroll
    for (int j = 0; j < 3; ++j) {
        const int nt = w * 3 + j;
        const int mat = nt >> 2;
        const int c = (nt & 3) * 16 + m;
        const float bias = (mat == 0) ? bq[c] : (mat == 1) ? bk[c] : bv[c];
        if (mat == 0) {
            #pragma unroll
            for (int r = 0; r < 4; ++r)
                q[(size_t)(gr0 + r) * HH + c] = f2bf((acc[j][r] + bias) * QSCALE);
        } else if (mat == 1) {
            #pragma unroll
            for (int r = 0; r < 4; ++r)
                k[(size_t)(gr0 + r) * HH + c] = f2bf(acc[j][r] + bias);
        } else {
            ushort4 pv;
            pv.x = f2bf(acc[j][0] + bias); pv.y = f2bf(acc[j][1] + bias);
            pv.z = f2bf(acc[j][2] + bias); pv.w = f2bf(acc[j][3] + bias);
            *(ushort4*)(vT + ((size_t)b_ * HH + c) * TT + t0) = pv;
        }
    }
}

// ---------------------------------------------------------------------------
// Kernel C (v7, unchanged from R9): causal flash attention, 8-way split-s,
// fixed-max exp2-domain softmax.  grid = 4*64*8 = 2048 blocks x 256 thr.
// ---------------------------------------------------------------------------
__global__ __launch_bounds__(256)
void attn_mfma_kernel(const ushort* __restrict__ q, const ushort* __restrict__ k,
                      const ushort* __restrict__ vT,
                      float* __restrict__ partL, ushort* __restrict__ partO)
{
    __shared__ ushort ks[64 * 72];
    __shared__ ushort vs[64 * 72];        // [d][s] (from vT)
    __shared__ ushort ps[4][16 * 72];     // wave-private P

    const int tid = threadIdx.x, w = tid >> 6, lane = tid & 63;
    const int m = lane & 15, quad = lane >> 4;
    const int pid = blockIdx.x;
    const int job = pid >> 3, split = pid & 7;
    const int b = job >> 6, tile = job & 63;
    const int i0 = tile * 64;
    const int nch = tile + 1;
    const int lo = (nch * split) >> 3, hi = (nch * (split + 1)) >> 3;

    const size_t qrow = ((size_t)b * TT + i0 + w * 16 + m) * HH;
    const uint4 aq0u = *(const uint4*)(q + qrow + quad * 8);
    const uint4 aq1u = *(const uint4*)(q + qrow + 32 + quad * 8);
    const short8 aq0 = *(const short8*)&aq0u;
    const short8 aq1 = *(const short8*)&aq1u;

    float lrow[4] = {0.f, 0.f, 0.f, 0.f};
    floatx4 oacc[4];
    #pragma unroll
    for (int nt = 0; nt < 4; ++nt) oacc[nt] = (floatx4){0.f, 0.f, 0.f, 0.f};

    const int iq0 = i0 + w * 16;
    for (int ch = lo; ch < hi; ++ch) {
        const int s0 = ch * 64;
        __syncthreads();
        const size_t kb = ((size_t)b * TT + s0) * HH;
        #pragma unroll
        for (int it = 0; it < 2; ++it) {
            const int t2 = it * 256 + tid;
            const int r = t2 >> 3, seg = t2 & 7;
            *(uint4*)(ks + r * 72 + seg * 8) = *(const uint4*)(k + kb + (size_t)r * HH + seg * 8);
            *(uint4*)(vs + r * 72 + seg * 8) = *(const uint4*)(vT + ((size_t)b * HH + r) * TT + s0 + seg * 8);
        }
        __syncthreads();

        floatx4 sc[4];
        #pragma unroll
        for (int nt = 0; nt < 4; ++nt) {
            const short8 b0 = *(const short8*)(ks + (nt * 16 + m) * 72 + quad * 8);
            const short8 b1 = *(const short8*)(ks + (nt * 16 + m) * 72 + 32 + quad * 8);
            floatx4 s_ = (floatx4){0.f, 0.f, 0.f, 0.f};
            s_ = __builtin_amdgcn_mfma_f32_16x16x32_bf16(aq0, b0, s_, 0, 0, 0);
            s_ = __builtin_amdgcn_mfma_f32_16x16x32_bf16(aq1, b1, s_, 0, 0, 0);
            sc[nt] = s_;
        }

        // fixed-max exp2-domain softmax.  p = 2^(s' - FIXMAX2); masked -> 0.
        const bool need_mask = (s0 + 63 > iq0);     // wave-uniform: diagonal chunk only
        #pragma unroll
        for (int r = 0; r < 4; ++r) {
            float t0 = sc[0][r] - FIXMAX2;
            float t1 = sc[1][r] - FIXMAX2;
            float t2 = sc[2][r] - FIXMAX2;
            float t3 = sc[3][r] - FIXMAX2;
            if (need_mask) {
                const int dlim = iq0 + quad * 4 + r - s0 - m;   // mask iff c*16 > dlim
                if (0  > dlim) t0 = -1e30f;
                if (16 > dlim) t1 = -1e30f;
                if (32 > dlim) t2 = -1e30f;
                if (48 > dlim) t3 = -1e30f;
            }
            const float p0 = __builtin_amdgcn_exp2f(t0);
            const float p1 = __builtin_amdgcn_exp2f(t1);
            const float p2 = __builtin_amdgcn_exp2f(t2);
            const float p3 = __builtin_amdgcn_exp2f(t3);
            lrow[r] += (p0 + p1) + (p2 + p3);
            ushort* pr = ps[w] + (quad * 4 + r) * 72;
            pr[m]      = f2bf(p0);
            pr[16 + m] = f2bf(p1);
            pr[32 + m] = f2bf(p2);
            pr[48 + m] = f2bf(p3);
        }

        // PV: A = P (LDS round-trip), B = vT rows
        #pragma unroll
        for (int ks_ = 0; ks_ < 2; ++ks_) {
            const short8 ap = *(const short8*)(ps[w] + m * 72 + ks_ * 32 + quad * 8);
            #pragma unroll
            for (int nt = 0; nt < 4; ++nt) {
                const short8 bv_ = *(const short8*)(vs + (nt * 16 + m) * 72 + ks_ * 32 + quad * 8);
                oacc[nt] = __builtin_amdgcn_mfma_f32_16x16x32_bf16(ap, bv_, oacc[nt], 0, 0, 0);
            }
        }
    }

    // reduce lrow across the 16 m-lanes (rows live in (quad, r))
    #pragma unroll
    for (int r = 0; r < 4; ++r) {
        float s = lrow[r];
        s += __shfl_xor(s, 1); s += __shfl_xor(s, 2);
        s += __shfl_xor(s, 4); s += __shfl_xor(s, 8);
        lrow[r] = s;
    }
    if (m == 0) {
        #pragma unroll
        for (int r = 0; r < 4; ++r)
            partL[(size_t)pid * 64 + w * 16 + quad * 4 + r] = lrow[r];
    }
    ushort* po = partO + ((size_t)pid * 64 + w * 16) * 64;
    #pragma unroll
    for (int r = 0; r < 4; ++r) {
        const int row = quad * 4 + r;
        #pragma unroll
        for (int nt = 0; nt < 4; ++nt)
            po[row * 64 + nt * 16 + m] = f2bf(oacc[nt][r]);
    }
}

// ---------------------------------------------------------------------------
// Kernel D (v2, unchanged from R9): combine 8 split partials (shared fixed
// max -> plain sums).  grid = 256 (job), 256 threads.
// ---------------------------------------------------------------------------
__global__ __launch_bounds__(256)
void attn_combine_kernel(const float* __restrict__ partL,
                         const ushort* __restrict__ partO, float* __restrict__ out)
{
    const int job = blockIdx.x;
    const int tid = threadIdx.x;
    const int row = tid >> 2, dq = tid & 3;

    float L = 0.f;
    #pragma unroll
    for (int s = 0; s < 8; ++s) L += partL[(size_t)(job * 8 + s) * 64 + row];
    const float inv = 1.f / L;

    float o[16];
    #pragma unroll
    for (int i = 0; i < 16; ++i) o[i] = 0.f;
    #pragma unroll
    for (int s = 0; s < 8; ++s) {
        const ushort* po = partO + (((size_t)(job * 8 + s) * 64 + row) * 64 + dq * 16);
        #pragma unroll
        for (int i2 = 0; i2 < 2; ++i2) {
            const ushort4 pa = *(const ushort4*)(po + i2 * 8);
            const ushort4 pb = *(const ushort4*)(po + i2 * 8 + 4);
            o[i2*8+0] += bf2f(pa.x); o[i2*8+1] += bf2f(pa.y);
            o[i2*8+2] += bf2f(pa.z); o[i2*8+3] += bf2f(pa.w);
            o[i2*8+4] += bf2f(pb.x); o[i2*8+5] += bf2f(pb.y);
            o[i2*8+6] += bf2f(pb.z); o[i2*8+7] += bf2f(pb.w);
        }
    }
    float4* dst = (float4*)(out + ((size_t)job * 64 + row) * 64 + dq * 16);
    #pragma unroll
    for (int i = 0; i < 4; ++i) {
        float4 v; v.x = o[i*4]*inv; v.y = o[i*4+1]*inv; v.z = o[i*4+2]*inv; v.w = o[i*4+3]*inv;
        dst[i] = v;
    }
}

extern "C" void kernel_launch(void* const* d_in, const int* in_sizes, int n_in,
                              void* d_out, int out_size, void* d_ws, size_t ws_size,
                              hipStream_t stream) {
    (void)in_sizes; (void)n_in; (void)out_size; (void)ws_size;
    const float* x  = (const float*)d_in[0];
    // d_in[1] = causal mask, structural -> unused
    const float* Wq = (const float*)d_in[2];
    const float* bq = (const float*)d_in[3];
    const float* Wk = (const float*)d_in[4];
    const float* bk = (const float*)d_in[5];
    const float* Wv = (const float*)d_in[6];
    const float* bv = (const float*)d_in[7];
    float* out = (float*)d_out;

    char* ws = (char*)d_ws;
    ushort* wT    = (ushort*)ws;                          // 384 KB @ 0
    ushort* qb    = (ushort*)(ws + 393216);               // 2 MB
    ushort* kb    = qb + (size_t)BB * TT * HH;            // 2 MB
    ushort* vTb   = kb + (size_t)BB * TT * HH;            // 2 MB
    float*  partL = (float*) (ws + 6684672);              // 512 KB (2048*64*4)
    ushort* partO = (ushort*)(ws + 7208960);              // 16.8 MB (total ~24 MB)

    wtrans_kernel   <<<48, 256, 0, stream>>>(Wq, Wk, Wv, wT);
    qkv_mfma_kernel <<<(BB * TT) / 16, 256, 0, stream>>>(x, wT, bq, bk, bv, qb, kb, vTb);
    attn_mfma_kernel<<<BB * 64 * 8, 256, 0, stream>>>(qb, kb, vTb, partL, partO);
    attn_combine_kernel<<<BB * 64, 256, 0, stream>>>(partL, partO, out);
}